// Round 1
// baseline (99.825 us; speedup 1.0000x reference)
//
#include <hip/hip_runtime.h>
#include <math.h>

// Problem constants
#define BB 8
#define HH 1024
#define TI 16            // i-rows per block
#define JC 128           // j per chunk
#define NJC (HH / JC)    // 8 chunks
#define C2PI 0.15915494309189535f   // 1/(2*pi): v_sin_f32 takes revolutions

// A-col tile layout: addr = k*SA_K + g*17 + ti  (k=jl&3, g=jl>>2, ti=0..15)
// SA_K odd => k-term is +1 mod 32 => conflict-free reads, <=2-way writes.
#define SA_K   545
#define SA_BUF (4 * SA_K)   // 2180 floats per buffer

// Fused single kernel: NO workspace usage. The previous 2-kernel version paid
// ~86us/iter of harness re-poison fill on the 268MB d_ws allocation (the two
// 43us fillBufferAligned dispatches dominating the profile). Each block owns
// 16 i-rows and loops over all j, so no cross-block reduction is needed.
__global__ __launch_bounds__(512, 4) void kuramoto_fused(
    const float* __restrict__ theta, const float* __restrict__ gamma,
    const float* __restrict__ A, const float* __restrict__ omega,
    const float* __restrict__ kappa, const float* __restrict__ alpha,
    float* __restrict__ out)
{
    const int blk = blockIdx.x;          // b*64 + it
    const int it  = blk & 63;
    const int b   = blk >> 6;
    const int i0  = it * TI;
    const int t   = threadIdx.x;
    const int ti  = t >> 5;              // 0..15  (i within tile)
    const int tj  = t & 31;              // 0..31  (j-lane)

    // theta_j for all 1024 j, pre-scaled to revolutions, float4 (d=0..3),
    // swizzled by j&3 so compute reads are lane-consecutive (no bank conflict).
    __shared__ float4 sTh4[HH];                 // 16 KB
    __shared__ float  sA[2 * SA_BUF];           // 17.4 KB, double-buffered A-col tile

    const float* Ab = A + (size_t)b * HH * HH;

    // ---- stage theta planes once ----
    #pragma unroll
    for (int r = 0; r < 2; ++r) {
        const int j = t + 512 * r;
        float4 v = ((const float4*)theta)[(size_t)b * HH + j];
        v.x *= C2PI; v.y *= C2PI; v.z *= C2PI; v.w *= C2PI;
        sTh4[(j & 3) * 256 + (j >> 2)] = v;
    }

    // ---- stage A column-panel chunk 0: A[b, j0+jl, i0+c], 128x16 ----
    const int sr = t >> 2;               // jl = 0..127
    const int sc = (t & 3) * 4;          // 0,4,8,12 (64B per row: full sectors)
    const float* colbase = Ab + (size_t)i0 + sc;
    {
        const float4 v = *(const float4*)&colbase[(size_t)sr * HH];
        float* dst = &sA[(sr & 3) * SA_K + (sr >> 2) * 17 + sc];
        dst[0] = v.x; dst[1] = v.y; dst[2] = v.z; dst[3] = v.w;
    }

    const int i = i0 + ti;
    const float4 thi = ((const float4*)theta)[(size_t)b * HH + i];
    const float tix = thi.x * C2PI, tiy = thi.y * C2PI,
                tiz = thi.z * C2PI, tiw = thi.w * C2PI;

    const float4* Arow4 = (const float4*)(Ab    + (size_t)i * HH);
    const float4* Al4   = (const float4*)(alpha + (size_t)i * HH);

    // chunk-0 row data prefetched before the barrier
    float4 ad = Arow4[tj];
    float4 al = Al4[tj];

    __syncthreads();

    float a0 = 0.f, a1 = 0.f, a2 = 0.f, a3 = 0.f;

    #pragma unroll 2
    for (int jc = 0; jc < NJC; ++jc) {
        const int buf = (jc & 1) ? SA_BUF : 0;
        const bool more = (jc + 1 < NJC);
        float4 adn, aln, vn;
        if (more) {   // T14 async-stage: issue next-chunk globals before compute
            adn = Arow4[32 * (jc + 1) + tj];
            aln = Al4  [32 * (jc + 1) + tj];
            vn  = *(const float4*)&colbase[(size_t)(JC * (jc + 1) + sr) * HH];
        }

        const float* sa = sA + buf + tj * 17 + ti;
        const int tb = 32 * jc + tj;
        #pragma unroll
        for (int k = 0; k < 4; ++k) {            // j = 128*jc + 4*tj + k
            const float  at   = sa[k * SA_K];                    // A[j,i]
            const float  alat = fmaxf(0.5f * ((&ad.x)[k] + at), 0.0f);
            const float  alc  = (&al.x)[k] * C2PI;
            const float4 tjv  = sTh4[k * 256 + tb];              // theta_j (scaled)
            a0 += alat * __builtin_amdgcn_sinf(tjv.x - (tix + alc));
            a1 += alat * __builtin_amdgcn_sinf(tjv.y - (tiy + alc));
            a2 += alat * __builtin_amdgcn_sinf(tjv.z - (tiz + alc));
            a3 += alat * __builtin_amdgcn_sinf(tjv.w - (tiw + alc));
        }

        if (more) {   // write next tile into the other buffer, swap row regs
            float* dst = &sA[(buf ^ SA_BUF) + (sr & 3) * SA_K + (sr >> 2) * 17 + sc];
            dst[0] = vn.x; dst[1] = vn.y; dst[2] = vn.z; dst[3] = vn.w;
            ad = adn; al = aln;
        }
        __syncthreads();   // one barrier per chunk (double-buffered)
    }

    // reduce across the 32 tj lanes (tj groups are lane-contiguous half-waves)
    #pragma unroll
    for (int off = 16; off >= 1; off >>= 1) {
        a0 += __shfl_down(a0, off, 32);
        a1 += __shfl_down(a1, off, 32);
        a2 += __shfl_down(a2, off, 32);
        a3 += __shfl_down(a3, off, 32);
    }

    if (tj == 0) {
        const float4 om = ((const float4*)omega)[i];
        const float4 kp = ((const float4*)kappa)[i];
        const float  g  = gamma[(size_t)b * HH + i];
        const float  inv = 1.0f / HH;   // K_COUP = 1, DT = 1
        float4 o;
        o.x = thi.x + om.x + a0 * inv + kp.x * (g - thi.x);
        o.y = thi.y + om.y + a1 * inv + kp.y * (g - thi.y);
        o.z = thi.z + om.z + a2 * inv + kp.z * (g - thi.z);
        o.w = thi.w + om.w + a3 * inv + kp.w * (g - thi.w);
        ((float4*)out)[(size_t)b * HH + i] = o;
    }
}

extern "C" void kernel_launch(void* const* d_in, const int* in_sizes, int n_in,
                              void* d_out, int out_size, void* d_ws, size_t ws_size,
                              hipStream_t stream) {
    const float* theta = (const float*)d_in[0];
    const float* gamma = (const float*)d_in[1];
    const float* A     = (const float*)d_in[2];
    const float* omega = (const float*)d_in[3];
    const float* kappa = (const float*)d_in[4];
    const float* alpha = (const float*)d_in[5];
    float* out = (float*)d_out;
    (void)d_ws; (void)ws_size;   // deliberately unused: avoids 268MB re-poison fills

    hipLaunchKernelGGL(kuramoto_fused, dim3(BB * (HH / TI)), dim3(512), 0, stream,
                       theta, gamma, A, omega, kappa, alpha, out);
}